// Round 4
// baseline (386.192 us; speedup 1.0000x reference)
//
#include <hip/hip_runtime.h>

// LogSignature depth-4, C=16, B=64, L=256, fp32.
// out per batch: [lvl1(16) | lvl2(256) | lvl3(4096) | lvl4(65536)] = 69904
//
// v5:
// k_dx: block j. Stages path[j] in LDS, writes dx1 [j][t][16] (time-major,
//   row 255 zeroed) and dxt [j][i][256] (component-major, col 255 zeroed).
//   Zero-padding step 255 makes every 64-step chunk a uniform 16-iter loop
//   (dx=0 => all recurrence updates are identity).
// k_scan: block (j,a), 512 threads = {chunk q(2b) | b(4b) | c0(3b)}; 4-way
//   time split (Chen) inside the block, 64 steps per chunk. Main loop uses
//   NO LDS (round-3 showed the uniform ds_read_b128 row broadcasts saturate
//   the per-CU LDS pipe): rows from dx1 (uniform addr -> SMEM/K$ or VMEM),
//   streams from dxt (L2-resident). Inner 32 FMAs done as 16 v_pk_fma_f32
//   via float2 + __builtin_elementwise_fma. launch_bounds(512,8) -> 4
//   blocks/CU = 32 waves/CU. Epilogue: 4 chunks' pure L4 sums merged in
//   LDS, single 16 KB coalesced write; per-chunk sig123 to ws.
// k_log: block (j,a). 3-stage Chen merge M <- M (x) X_s (s=1..3): level-4
//   cross terms accumulate in registers, M1/M2/M3 merged in LDS; then log
//   correction (same formulas as v4) on merged S, RMW on out L4.
//
// ws (floats): dx1 [64][256][16] | dxt [64][16][256] | sig [4][64][4368]
// total 1,642,496 floats ~ 6.6 MB.

#define NC 16
#define NL 256
#define NB 64
#define OUTB 69904
#define SIG123 4368
#define OFF_L2 16
#define OFF_L3 272
#define OFF_L4 4368

#define DX1_OFF 0
#define DXT_OFF 262144
#define SIG_OFF 524288

typedef float v2f __attribute__((ext_vector_type(2)));

// One block per batch j: stage path[j] (16 KB) in LDS, emit both dx layouts,
// zero-padded at step 255.
__global__ __launch_bounds__(256) void k_dx(const float* __restrict__ path,
                                            float* __restrict__ dx1,
                                            float* __restrict__ dxt) {
    const int j = blockIdx.x;
    const int tid = threadIdx.x;
    __shared__ float L[NL * NC];  // 16 KB, [t][i]

    const float* pj = path + (size_t)j * NL * NC;
#pragma unroll
    for (int k = 0; k < 4; ++k) {
        const int f = tid + k * 256;  // float4 index
        *(float4*)&L[f * 4] = *(const float4*)&pj[f * 4];
    }
    __syncthreads();

    // time-major diffs (coalesced), row 255 = 0
    float* d1 = dx1 + (size_t)j * NL * NC;
#pragma unroll
    for (int k = 0; k < 16; ++k) {
        const int f = tid + k * 256;
        d1[f] = (f < (NL - 1) * NC) ? (L[f + NC] - L[f]) : 0.f;
    }

    // component-major diffs: iter k = component, lane = t; col 255 = 0
    float* dt = dxt + (size_t)j * NC * 256;
#pragma unroll
    for (int k = 0; k < NC; ++k) {
        const int t = tid;
        dt[k * 256 + t] = (t < NL - 1) ? (L[(t + 1) * NC + k] - L[t * NC + k]) : 0.f;
    }
}

// Chunk-local signature scan, 4 chunks of 64 steps per block (step 255 is a
// zero step). Thread (q,b,c0) owns s3/s4 for rows (a,b,c0,*) and (a,b,c0+8,*)
// of its chunk.
__global__ __launch_bounds__(512, 8) void k_scan(const float* __restrict__ dx1,
                                                 const float* __restrict__ dxt,
                                                 float* __restrict__ out,
                                                 float* __restrict__ sig) {
    const int bid = blockIdx.x;
    const int j = bid >> 4;
    const int a = bid & 15;
    const int tid = threadIdx.x;
    const int qc = tid >> 7;         // time chunk 0..3 -> steps [qc*64, qc*64+64)
    const int b = (tid >> 3) & 15;
    const int c0 = tid & 7;          // owns c0 and c0+8

    const float* row0 = dx1 + (size_t)j * NL * NC;          // [t][16], uniform
    const float* ra = dxt + ((size_t)j * NC + a) * 256;     // uniform
    const float* rb = dxt + ((size_t)j * NC + b) * 256;     // per-lane streams
    const float* rc0 = dxt + ((size_t)j * NC + c0) * 256;
    const float* rc1 = rc0 + 8 * 256;

    v2f s4a[8], s4b[8];
#pragma unroll
    for (int d = 0; d < 8; ++d) { s4a[d] = (v2f){0.f, 0.f}; s4b[d] = (v2f){0.f, 0.f}; }
    float s3_0 = 0.f, s3_1 = 0.f, s2ab = 0.f, s1a = 0.f;

    int t = qc * 64;
    for (int it = 0; it < 16; ++it, t += 4) {
        const float4 va = *(const float4*)(ra + t);   // uniform
        const float4 vb = *(const float4*)(rb + t);   // per-lane (8 lines/wave, L2)
        const float4 vc0 = *(const float4*)(rc0 + t);
        const float4 vc1 = *(const float4*)(rc1 + t);
#pragma unroll
        for (int u = 0; u < 4; ++u) {
            const float* r = row0 + (t + u) * NC;     // uniform row
            const float4 q0 = *(const float4*)(r);
            const float4 q1 = *(const float4*)(r + 4);
            const float4 q2 = *(const float4*)(r + 8);
            const float4 q3 = *(const float4*)(r + 12);
            const float dxa = (u == 0) ? va.x : (u == 1) ? va.y : (u == 2) ? va.z : va.w;
            const float dxb = (u == 0) ? vb.x : (u == 1) ? vb.y : (u == 2) ? vb.z : vb.w;
            const float dxc0 = (u == 0) ? vc0.x : (u == 1) ? vc0.y : (u == 2) ? vc0.z : vc0.w;
            const float dxc1 = (u == 0) ? vc1.x : (u == 1) ? vc1.y : (u == 2) ? vc1.z : vc1.w;

            const float P = dxb * s1a;
            const float Q = dxb * dxa;
            const float pre4 = fmaf(1.f / 6.f, P, fmaf(1.f / 24.f, Q, 0.5f * s2ab));
            const float U = fmaf(0.5f, P, fmaf(1.f / 6.f, Q, s2ab));
            const float T0 = fmaf(dxc0, pre4, s3_0);
            const float T1 = fmaf(dxc1, pre4, s3_1);

            const v2f dv2[8] = {{q0.x, q0.y}, {q0.z, q0.w}, {q1.x, q1.y}, {q1.z, q1.w},
                                {q2.x, q2.y}, {q2.z, q2.w}, {q3.x, q3.y}, {q3.z, q3.w}};
            const v2f T0v = {T0, T0};
            const v2f T1v = {T1, T1};
#pragma unroll
            for (int d = 0; d < 8; ++d) {
                s4a[d] = __builtin_elementwise_fma(dv2[d], T0v, s4a[d]);  // v_pk_fma_f32
                s4b[d] = __builtin_elementwise_fma(dv2[d], T1v, s4b[d]);
            }
            s3_0 = fmaf(dxc0, U, s3_0);
            s3_1 = fmaf(dxc1, U, s3_1);
            s2ab = fmaf(dxb, fmaf(0.5f, dxa, s1a), s2ab);
            s1a += dxa;
        }
    }

    // epilogue: sum the 4 chunks' pure L4 contributions in LDS, one write.
    __shared__ float ls[4096];  // 16 KB
    const int base = b * 256 + c0 * 16;
#pragma unroll
    for (int ph = 0; ph < 4; ++ph) {
        if (qc == ph) {
            if (ph == 0) {
#pragma unroll
                for (int d = 0; d < 4; ++d) {
                    *(float4*)&ls[base + d * 4] = make_float4(
                        s4a[2 * d].x, s4a[2 * d].y, s4a[2 * d + 1].x, s4a[2 * d + 1].y);
                    *(float4*)&ls[base + 128 + d * 4] = make_float4(
                        s4b[2 * d].x, s4b[2 * d].y, s4b[2 * d + 1].x, s4b[2 * d + 1].y);
                }
            } else {
#pragma unroll
                for (int d = 0; d < 4; ++d) {
                    float4 v0 = *(const float4*)&ls[base + d * 4];
                    v0.x += s4a[2 * d].x; v0.y += s4a[2 * d].y;
                    v0.z += s4a[2 * d + 1].x; v0.w += s4a[2 * d + 1].y;
                    *(float4*)&ls[base + d * 4] = v0;
                    float4 v1 = *(const float4*)&ls[base + 128 + d * 4];
                    v1.x += s4b[2 * d].x; v1.y += s4b[2 * d].y;
                    v1.z += s4b[2 * d + 1].x; v1.w += s4b[2 * d + 1].y;
                    *(float4*)&ls[base + 128 + d * 4] = v1;
                }
            }
        }
        __syncthreads();
    }
    {
        float* o4 = out + (size_t)j * OUTB + OFF_L4 + a * 4096;
#pragma unroll
        for (int k = 0; k < 2; ++k) {
            const int f = tid + k * 512;  // float4 index 0..1023
            *(float4*)(o4 + f * 4) = *(const float4*)&ls[f * 4];
        }
    }

    // levels 1-3 of this thread's chunk
    float* sg = sig + ((size_t)qc * NB + j) * SIG123;
    sg[OFF_L3 + (a * 16 + b) * 16 + c0] = s3_0;
    sg[OFF_L3 + (a * 16 + b) * 16 + c0 + 8] = s3_1;
    if (c0 == 0) sg[OFF_L2 + a * 16 + b] = s2ab;
    if ((tid & 127) == 0) sg[a] = s1a;
}

// 3-stage Chen merge of the 4 chunk signatures + log correction.
// M starts as X0; for s=1..3: level-4 cross terms (M1 x X3 + M2 x X2 + M3 x X1)
// accumulate into registers using OLD M, then M123 <- M (x) X_s in LDS.
// Final: out L4 = P(=sum X4, already in out) + acc + log correction on merged S.
__global__ __launch_bounds__(256, 4) void k_log(const float* __restrict__ sig,
                                                float* __restrict__ out) {
    const int bid = blockIdx.x;
    const int j = bid >> 4;
    const int a = bid & 15;
    const int tid = threadIdx.x;
    const int p16 = tid >> 4;
    const int r16 = tid & 15;

    __shared__ float M1[16];
    __shared__ float M2[256];
    __shared__ float M3[4096];

    const float* X0 = sig + (size_t)j * SIG123;
    if (tid < 16) M1[tid] = X0[tid];
    M2[tid] = X0[OFF_L2 + tid];
#pragma unroll
    for (int k = 0; k < 16; ++k) M3[k * 256 + tid] = X0[OFF_L3 + k * 256 + tid];

    float4 acc[4];
#pragma unroll
    for (int k = 0; k < 4; ++k) acc[k] = make_float4(0.f, 0.f, 0.f, 0.f);
    __syncthreads();

    for (int s = 1; s < 4; ++s) {
        const float* Xs = sig + ((size_t)s * NB + j) * SIG123;
        const float m1a = M1[a];
        float4 m3n[4];
#pragma unroll
        for (int k = 0; k < 4; ++k) {
            const int f = tid + k * 256;   // float4 index 0..1023
            const int m0 = f * 4;          // element offset: bb*256 + cc*16 + d0
            const int bb = m0 >> 8;
            const int cc = (m0 >> 4) & 15;
            const float4 x3 = *(const float4*)(Xs + OFF_L3 + m0);
            const float4 x2 = *(const float4*)(Xs + OFF_L2 + (m0 & 255));
            const float4 x1 = *(const float4*)(Xs + (m0 & 15));
            const float4 m3f = *(const float4*)(&M3[m0]);
            const float m2ab = M2[a * 16 + bb];
            const float m3abc = M3[a * 256 + (m0 >> 4)];
            const float m2pq = M2[bb * 16 + cc];
            const float m1p = M1[bb];
            // level-4 cross terms (old M x new chunk)
            acc[k].x += fmaf(m1a, x3.x, fmaf(m2ab, x2.x, m3abc * x1.x));
            acc[k].y += fmaf(m1a, x3.y, fmaf(m2ab, x2.y, m3abc * x1.y));
            acc[k].z += fmaf(m1a, x3.z, fmaf(m2ab, x2.z, m3abc * x1.z));
            acc[k].w += fmaf(m1a, x3.w, fmaf(m2ab, x2.w, m3abc * x1.w));
            // level-3 merge: M3' = M3 + X3 + M1 x X2 + M2 x X1
            m3n[k].x = m3f.x + x3.x + fmaf(m1p, x2.x, m2pq * x1.x);
            m3n[k].y = m3f.y + x3.y + fmaf(m1p, x2.y, m2pq * x1.y);
            m3n[k].z = m3f.z + x3.z + fmaf(m1p, x2.z, m2pq * x1.z);
            m3n[k].w = m3f.w + x3.w + fmaf(m1p, x2.w, m2pq * x1.w);
        }
        const float m2new = M2[tid] + Xs[OFF_L2 + tid] + M1[p16] * Xs[r16];
        float m1new = 0.f;
        if (tid < 16) m1new = M1[tid] + Xs[tid];
        __syncthreads();
#pragma unroll
        for (int k = 0; k < 4; ++k) *(float4*)(&M3[(tid + k * 256) * 4]) = m3n[k];
        M2[tid] = m2new;
        if (tid < 16) M1[tid] = m1new;
        __syncthreads();
    }

    // log correction on merged S (= M), RMW on out L4 (holds sum of pure X4).
    const float s1a = M1[a];
    float* outj = out + (size_t)j * OUTB;
    float* o4 = outj + OFF_L4 + a * 4096;
    const float Ac = -0.5f * s1a;

#pragma unroll
    for (int k = 0; k < 4; ++k) {
        const int f = tid + k * 256;
        const int m0 = f * 4;
        const int bb = m0 >> 8;
        const int cc = (m0 >> 4) & 15;
        const float s1b = M1[bb], s1c = M1[cc];
        const float s2ab = M2[a * 16 + bb];
        const float s2bc = M2[bb * 16 + cc];
        const float s3abc = M3[a * 256 + (m0 >> 4)];

        const float4 p4 = *(const float4*)(o4 + m0);
        const float4 v3 = *(const float4*)(&M3[m0]);
        const float4 v2 = *(const float4*)(&M2[m0 & 255]);
        const float4 v1 = *(const float4*)(&M1[m0 & 15]);

        const float Bv = fmaf((1.f / 3.f) * s1a, s1b, -0.5f * s2ab);
        const float Cv = -0.5f * s3abc + (1.f / 3.f) * fmaf(s1a, s2bc, s2ab * s1c)
                         - 0.25f * s1a * s1b * s1c;
        float4 rr;
        rr.x = p4.x + acc[k].x;
        rr.y = p4.y + acc[k].y;
        rr.z = p4.z + acc[k].z;
        rr.w = p4.w + acc[k].w;
        rr.x = fmaf(Ac, v3.x, rr.x) + fmaf(Bv, v2.x, Cv * v1.x);
        rr.y = fmaf(Ac, v3.y, rr.y) + fmaf(Bv, v2.y, Cv * v1.y);
        rr.z = fmaf(Ac, v3.z, rr.z) + fmaf(Bv, v2.z, Cv * v1.z);
        rr.w = fmaf(Ac, v3.w, rr.w) + fmaf(Bv, v2.w, Cv * v1.w);
        *(float4*)(o4 + m0) = rr;
    }

    // level 3 (coalesced): note s2bc = M2[tid] since tid = b*16+c here.
    {
        const float s1b = M1[p16], s1c = M1[r16];
        const float s2ab = M2[a * 16 + p16];
        const float s2bc = M2[tid];
        const float s3abc = M3[a * 256 + tid];
        const float r3 = s3abc - 0.5f * fmaf(s1a, s2bc, s2ab * s1c)
                         + (1.f / 3.f) * s1a * s1b * s1c;
        outj[OFF_L3 + a * 256 + tid] = r3;
    }
    // level 2
    if (tid < 16) outj[OFF_L2 + a * 16 + tid] = fmaf(-0.5f * s1a, M1[tid], M2[a * 16 + tid]);
    // level 1
    if (tid == 0) outj[a] = s1a;
}

extern "C" void kernel_launch(void* const* d_in, const int* in_sizes, int n_in,
                              void* d_out, int out_size, void* d_ws, size_t ws_size,
                              hipStream_t stream) {
    const float* path = (const float*)d_in[0];
    float* out = (float*)d_out;
    float* ws = (float*)d_ws;
    float* dx1 = ws + DX1_OFF;
    float* dxt = ws + DXT_OFF;
    float* sig = ws + SIG_OFF;

    k_dx<<<NB, 256, 0, stream>>>(path, dx1, dxt);
    k_scan<<<NB * 16, 512, 0, stream>>>(dx1, dxt, out, sig);
    k_log<<<NB * 16, 256, 0, stream>>>(sig, out);
}

// Round 5
// 171.848 us; speedup vs baseline: 2.2473x; 2.2473x over previous
//
#include <hip/hip_runtime.h>

// LogSignature depth-4, C=16, B=64, L=256, fp32.
// out per batch: [lvl1(16) | lvl2(256) | lvl3(4096) | lvl4(65536)] = 69904
//
// v6 = v5's load/compute structure at v4's register budget.
// k_dx: block j. dx1 [j][t][16] time-major (row 255 zeroed) and dxt
//   [j][i][256] component-major (col 255 zeroed). Padding makes both 128-step
//   chunks uniform 32x(4-step) loops, no tail.
// k_scan: block (j,a), 256 threads = {h(1b) | b(4b) | c0(3b)}, c-pair per
//   thread, 2-way in-block time split (Chen). Main loop uses NO LDS (the v3/v4
//   uniform ds_read_b128 row broadcasts saturated the per-CU LDS pipe): rows
//   from dx1 (uniform addr, L1-broadcast), streams from dxt (L2-resident).
//   Inner 32 FMAs as 16 v_pk_fma_f32 (float2 + __builtin_elementwise_fma).
//   launch_bounds(256,4) -> 128-VGPR budget, NO SPILL (v5's 512/8 forced a
//   64-VGPR budget and spilled the accumulators: 640 MB scratch writes).
//   Epilogue: A4+B4 merged in LDS, one 16 KB write; sig123 per chunk to ws.
// k_log: v4's verified 2-chunk Chen merge + log correction. B3 from global
//   (L2-resident), ~20 KB LDS.
//
// ws (floats): dx1 262144 | dxt 262144 | sigA 64*4368 | sigB 64*4368  (~4.3 MB)

#define NC 16
#define NL 256
#define NB 64
#define OUTB 69904
#define SIG123 4368
#define OFF_L2 16
#define OFF_L3 272
#define OFF_L4 4368

#define DX1_OFF 0
#define DXT_OFF 262144
#define SIGA_OFF 524288
#define SIGB_OFF (524288 + NB * SIG123)

typedef float v2f __attribute__((ext_vector_type(2)));

// One block per batch j: stage path[j] (16 KB) in LDS, emit both dx layouts,
// zero-padded at step 255.
__global__ __launch_bounds__(256) void k_dx(const float* __restrict__ path,
                                            float* __restrict__ dx1,
                                            float* __restrict__ dxt) {
    const int j = blockIdx.x;
    const int tid = threadIdx.x;
    __shared__ float L[NL * NC];  // 16 KB, [t][i]

    const float* pj = path + (size_t)j * NL * NC;
#pragma unroll
    for (int k = 0; k < 4; ++k) {
        const int f = tid + k * 256;  // float4 index
        *(float4*)&L[f * 4] = *(const float4*)&pj[f * 4];
    }
    __syncthreads();

    // time-major diffs (coalesced), row 255 = 0
    float* d1 = dx1 + (size_t)j * NL * NC;
#pragma unroll
    for (int k = 0; k < 16; ++k) {
        const int f = tid + k * 256;
        d1[f] = (f < (NL - 1) * NC) ? (L[f + NC] - L[f]) : 0.f;
    }

    // component-major diffs: iter k = component, lane = t; col 255 = 0
    float* dt = dxt + (size_t)j * NC * 256;
#pragma unroll
    for (int k = 0; k < NC; ++k) {
        const int t = tid;
        dt[k * 256 + t] = (t < NL - 1) ? (L[(t + 1) * NC + k] - L[t * NC + k]) : 0.f;
    }
}

// Chunk-local signature scan: 2 chunks of 128 steps per block (step 255 is a
// zero step). Thread (h,b,c0) owns s3/s4 for rows (a,b,c0,*) and (a,b,c0+8,*).
__global__ __launch_bounds__(256, 4) void k_scan(const float* __restrict__ dx1,
                                                 const float* __restrict__ dxt,
                                                 float* __restrict__ out,
                                                 float* __restrict__ sigA,
                                                 float* __restrict__ sigB) {
    const int bid = blockIdx.x;
    const int j = bid >> 4;
    const int a = bid & 15;
    const int tid = threadIdx.x;
    const int h = tid >> 7;          // time chunk: 0 -> [0,128), 1 -> [128,256)
    const int b = (tid >> 3) & 15;
    const int c0 = tid & 7;          // owns c0 and c0+8

    const float* row0 = dx1 + (size_t)j * NL * NC;          // [t][16], uniform
    const float* ra = dxt + ((size_t)j * NC + a) * 256;     // uniform
    const float* rb = dxt + ((size_t)j * NC + b) * 256;     // per-lane streams
    const float* rc0 = dxt + ((size_t)j * NC + c0) * 256;
    const float* rc1 = rc0 + 8 * 256;

    v2f s4a[8], s4b[8];
#pragma unroll
    for (int d = 0; d < 8; ++d) { s4a[d] = (v2f){0.f, 0.f}; s4b[d] = (v2f){0.f, 0.f}; }
    float s3_0 = 0.f, s3_1 = 0.f, s2ab = 0.f, s1a = 0.f;

    int t = h * 128;
    for (int it = 0; it < 32; ++it, t += 4) {
        const float4 va = *(const float4*)(ra + t);   // uniform
        const float4 vb = *(const float4*)(rb + t);   // 8 lines/wave, L2-resident
        const float4 vc0 = *(const float4*)(rc0 + t);
        const float4 vc1 = *(const float4*)(rc1 + t);
#pragma unroll
        for (int u = 0; u < 4; ++u) {
            const float* r = row0 + (t + u) * NC;     // uniform row, L1 broadcast
            const float4 q0 = *(const float4*)(r);
            const float4 q1 = *(const float4*)(r + 4);
            const float4 q2 = *(const float4*)(r + 8);
            const float4 q3 = *(const float4*)(r + 12);
            const float dxa = (u == 0) ? va.x : (u == 1) ? va.y : (u == 2) ? va.z : va.w;
            const float dxb = (u == 0) ? vb.x : (u == 1) ? vb.y : (u == 2) ? vb.z : vb.w;
            const float dxc0 = (u == 0) ? vc0.x : (u == 1) ? vc0.y : (u == 2) ? vc0.z : vc0.w;
            const float dxc1 = (u == 0) ? vc1.x : (u == 1) ? vc1.y : (u == 2) ? vc1.z : vc1.w;

            const float P = dxb * s1a;
            const float Q = dxb * dxa;
            const float pre4 = fmaf(1.f / 6.f, P, fmaf(1.f / 24.f, Q, 0.5f * s2ab));
            const float U = fmaf(0.5f, P, fmaf(1.f / 6.f, Q, s2ab));
            const float T0 = fmaf(dxc0, pre4, s3_0);
            const float T1 = fmaf(dxc1, pre4, s3_1);

            const v2f dv2[8] = {{q0.x, q0.y}, {q0.z, q0.w}, {q1.x, q1.y}, {q1.z, q1.w},
                                {q2.x, q2.y}, {q2.z, q2.w}, {q3.x, q3.y}, {q3.z, q3.w}};
            const v2f T0v = {T0, T0};
            const v2f T1v = {T1, T1};
#pragma unroll
            for (int d = 0; d < 8; ++d) {
                s4a[d] = __builtin_elementwise_fma(dv2[d], T0v, s4a[d]);  // v_pk_fma_f32
                s4b[d] = __builtin_elementwise_fma(dv2[d], T1v, s4b[d]);
            }
            s3_0 = fmaf(dxc0, U, s3_0);
            s3_1 = fmaf(dxc1, U, s3_1);
            s2ab = fmaf(dxb, fmaf(0.5f, dxa, s1a), s2ab);
            s1a += dxa;
        }
    }

    // epilogue: merge A4 + B4 in LDS (both halves live in this block),
    // write ONE 16 KB slice. Cross terms are k_log's job.
    __shared__ float ls[4096];  // 16 KB
    const int base = b * 256 + c0 * 16;
    if (h == 0) {
#pragma unroll
        for (int d = 0; d < 4; ++d) {
            *(float4*)&ls[base + d * 4] = make_float4(
                s4a[2 * d].x, s4a[2 * d].y, s4a[2 * d + 1].x, s4a[2 * d + 1].y);
            *(float4*)&ls[base + 128 + d * 4] = make_float4(
                s4b[2 * d].x, s4b[2 * d].y, s4b[2 * d + 1].x, s4b[2 * d + 1].y);
        }
    }
    __syncthreads();
    if (h == 1) {
#pragma unroll
        for (int d = 0; d < 4; ++d) {
            float4 v0 = *(const float4*)&ls[base + d * 4];
            v0.x += s4a[2 * d].x; v0.y += s4a[2 * d].y;
            v0.z += s4a[2 * d + 1].x; v0.w += s4a[2 * d + 1].y;
            *(float4*)&ls[base + d * 4] = v0;
            float4 v1 = *(const float4*)&ls[base + 128 + d * 4];
            v1.x += s4b[2 * d].x; v1.y += s4b[2 * d].y;
            v1.z += s4b[2 * d + 1].x; v1.w += s4b[2 * d + 1].y;
            *(float4*)&ls[base + 128 + d * 4] = v1;
        }
    }
    __syncthreads();
    {
        float* o4 = out + (size_t)j * OUTB + OFF_L4 + a * 4096;
#pragma unroll
        for (int k = 0; k < 4; ++k) {
            const int f = tid + k * 256;  // float4 index 0..1023
            *(float4*)(o4 + f * 4) = *(const float4*)&ls[f * 4];
        }
    }

    // levels 1-3 of this thread's chunk
    float* sg = (h ? sigB : sigA) + (size_t)j * SIG123;
    sg[OFF_L3 + (a * 16 + b) * 16 + c0] = s3_0;
    sg[OFF_L3 + (a * 16 + b) * 16 + c0 + 8] = s3_1;
    if (c0 == 0) sg[OFF_L2 + a * 16 + b] = s2ab;
    if ((tid & 127) == 0) sg[a] = s1a;
}

// Chen cross-terms (S4 = [A4+B4] + A1(x)B3 + A2(x)B2 + A3(x)B1) + log
// correction. Block (j,a). Merged S1/S2/S3 in LDS (~20 KB); B3 from global
// (L2-resident, 17 KB per batch shared by 16 blocks).
__global__ __launch_bounds__(256) void k_log(const float* __restrict__ sigA,
                                             const float* __restrict__ sigB,
                                             float* __restrict__ out) {
    const int bid = blockIdx.x;
    const int j = bid >> 4;
    const int a = bid & 15;
    const int tid = threadIdx.x;
    const int q = tid >> 4;
    const int r = tid & 15;

    const float* A = sigA + (size_t)j * SIG123;
    const float* Bp = sigB + (size_t)j * SIG123;

    __shared__ float S1m[16], B1s[16], A2s[16];
    __shared__ float S2m[256], B2s[256], A3s[256];
    __shared__ float S3m[4096];

    const float b1r = Bp[r];             // B1[r]
    const float b2t = Bp[OFF_L2 + tid];  // B2[q,r]

    if (tid < 16) {
        const float bb = Bp[tid];
        B1s[tid] = bb;
        S1m[tid] = A[tid] + bb;               // S1 = A1 + B1
        A2s[tid] = A[OFF_L2 + a * 16 + tid];  // A2[a,:]
    }
    B2s[tid] = b2t;
    S2m[tid] = A[OFF_L2 + tid] + b2t + A[q] * b1r;  // S2 = A2 + B2 + A1(x)B1
    A3s[tid] = A[OFF_L3 + a * 256 + tid];           // A3[a,:,:]
#pragma unroll
    for (int k = 0; k < 16; ++k) {  // S3[p=k,q,r] = A3 + B3 + A1[p]B2[qr] + A2[pq]B1[r]
        const int m = k * 256 + tid;
        S3m[m] = A[OFF_L3 + m] + Bp[OFF_L3 + m] + A[k] * b2t + A[OFF_L2 + k * 16 + q] * b1r;
    }
    __syncthreads();

    const float s1a = S1m[a];
    const float A1a = A[a];
    float* outj = out + (size_t)j * OUTB;
    float* o4 = outj + OFF_L4 + a * 4096;
    const float Ac = -0.5f * s1a;

#pragma unroll
    for (int k = 0; k < 4; ++k) {
        const int f = tid + k * 256;
        const int m0 = f * 4;  // element offset: b*256 + c*16 + d0
        const int bb = m0 >> 8;
        const int cc = (m0 >> 4) & 15;
        const float s1b = S1m[bb], s1c = S1m[cc];
        const float s2ab = S2m[a * 16 + bb];
        const float s2bc = S2m[bb * 16 + cc];
        const float s3abc = S3m[a * 256 + (m0 >> 4)];  // merged S3[a,b,c]
        const float a3x = A3s[m0 >> 4];                // A3[a,b,c]
        const float a2x = A2s[bb];                     // A2[a,b]

        const float4 a4 = *(const float4*)(o4 + m0);            // A4+B4
        const float4 b3v = *(const float4*)(Bp + OFF_L3 + m0);  // B3[b,c,d..] (L2)
        const float4 b2v = *(const float4*)(&B2s[m0 & 255]);
        const float4 b1v = *(const float4*)(&B1s[m0 & 15]);
        const float4 v3 = *(const float4*)(&S3m[m0]);
        const float4 v2 = *(const float4*)(&S2m[m0 & 255]);
        const float4 v1 = *(const float4*)(&S1m[m0 & 15]);

        const float Bv = fmaf((1.f / 3.f) * s1a, s1b, -0.5f * s2ab);
        const float Cv = -0.5f * s3abc + (1.f / 3.f) * fmaf(s1a, s2bc, s2ab * s1c)
                         - 0.25f * s1a * s1b * s1c;
        float4 rr;
        // merged S4 = (A4+B4) + A1[a]B3[bcd] + A2[ab]B2[cd] + A3[abc]B1[d]
        rr.x = a4.x + fmaf(A1a, b3v.x, fmaf(a2x, b2v.x, a3x * b1v.x));
        rr.y = a4.y + fmaf(A1a, b3v.y, fmaf(a2x, b2v.y, a3x * b1v.y));
        rr.z = a4.z + fmaf(A1a, b3v.z, fmaf(a2x, b2v.z, a3x * b1v.z));
        rr.w = a4.w + fmaf(A1a, b3v.w, fmaf(a2x, b2v.w, a3x * b1v.w));
        // log correction
        rr.x = fmaf(Ac, v3.x, rr.x) + fmaf(Bv, v2.x, Cv * v1.x);
        rr.y = fmaf(Ac, v3.y, rr.y) + fmaf(Bv, v2.y, Cv * v1.y);
        rr.z = fmaf(Ac, v3.z, rr.z) + fmaf(Bv, v2.z, Cv * v1.z);
        rr.w = fmaf(Ac, v3.w, rr.w) + fmaf(Bv, v2.w, Cv * v1.w);
        *(float4*)(o4 + m0) = rr;
    }

    // level 3 (coalesced)
    {
        const float s1b = S1m[q], s1c = S1m[r];
        const float s2ab = S2m[a * 16 + q];
        const float s2bc = S2m[q * 16 + r];
        const float s3abc = S3m[a * 256 + tid];
        const float r3 = s3abc - 0.5f * fmaf(s1a, s2bc, s2ab * s1c)
                         + (1.f / 3.f) * s1a * s1b * s1c;
        outj[OFF_L3 + a * 256 + tid] = r3;
    }
    // level 2
    if (tid < 16) outj[OFF_L2 + a * 16 + tid] = fmaf(-0.5f * s1a, S1m[tid], S2m[a * 16 + tid]);
    // level 1
    if (tid == 0) outj[a] = s1a;
}

extern "C" void kernel_launch(void* const* d_in, const int* in_sizes, int n_in,
                              void* d_out, int out_size, void* d_ws, size_t ws_size,
                              hipStream_t stream) {
    const float* path = (const float*)d_in[0];
    float* out = (float*)d_out;
    float* ws = (float*)d_ws;
    float* dx1 = ws + DX1_OFF;
    float* dxt = ws + DXT_OFF;
    float* sigA = ws + SIGA_OFF;
    float* sigB = ws + SIGB_OFF;

    k_dx<<<NB, 256, 0, stream>>>(path, dx1, dxt);
    k_scan<<<NB * 16, 256, 0, stream>>>(dx1, dxt, out, sigA, sigB);
    k_log<<<NB * 16, 256, 0, stream>>>(sigA, sigB, out);
}

// Round 6
// 107.523 us; speedup vs baseline: 3.5917x; 1.5982x over previous
//
#include <hip/hip_runtime.h>
#include <hip/hip_cooperative_groups.h>

namespace cg = cooperative_groups;

// LogSignature depth-4, C=16, B=64, L=256, fp32.
// out per batch: [lvl1(16) | lvl2(256) | lvl3(4096) | lvl4(65536)] = 69904
//
// v7: single cooperative kernel (grid exactly co-resident: 1024 blocks x 256
// thr, 36KB LDS, <=128 VGPR -> 4 blocks/CU x 256 CU).
//   phase 1 = v4's proven LDS scan (block (j,a), c-pair, 2-way in-block time
//     split; dual LDS layout Lp/Lc; step 255 zero-padded -> uniform 32x4 loop,
//     no tail; inner 32 FMAs as 16 v_pk_fma_f32). Pure A4+B4 sum stays in
//     LDS; sig123 per chunk -> ws (L2-hot).
//   grid.sync()  (cooperative; __threadfence before)
//   phase 2 = v4's k_log body (Chen cross terms + log correction), with the
//     L4 partial read from LDS instead of a 16.7MB global RMW round-trip.
// Eliminates k_log's ~55us (kernel + L4 re-read + launch gap).
// Fallback (attribute query, no stream ops): split v4 pair.
//
// ws (floats): sigA [64][4368] | sigB [64][4368]  (~2.2 MB)

#define NC 16
#define NL 256
#define NB 64
#define OUTB 69904
#define SIG123 4368
#define OFF_L2 16
#define OFF_L3 272
#define OFF_L4 4368
#define LCS 260  // padded component-major stride (floats)

#define SIGA_OFF 0
#define SIGB_OFF (NB * SIG123)

typedef float v2f __attribute__((ext_vector_type(2)));

template <int FUSED>
__global__ __launch_bounds__(256, 4) void k_fused(const float* __restrict__ path,
                                                  float* __restrict__ out,
                                                  float* __restrict__ sigA,
                                                  float* __restrict__ sigB) {
    const int bid = blockIdx.x;
    const int j = bid >> 4;
    const int a = bid & 15;
    const int tid = threadIdx.x;
    const int h = tid >> 7;          // time chunk: 0 -> [0,128), 1 -> [128,256)
    const int b = (tid >> 3) & 15;
    const int c0 = tid & 7;          // owns c0 and c0+8

    __shared__ float shA[4096];      // path -> time-major diffs (Lp); later pure-L4 sums (ls)
    __shared__ float shB[4912];      // comp-major diffs (Lc, 4160 used); later merge arrays

    float* Lp = shA;
    float* Lc = shB;

    // ---- stage path[j] (16 KB, coalesced) ----
    const float* pj = path + (size_t)j * NL * NC;
#pragma unroll
    for (int k = 0; k < 4; ++k) {
        const int f = tid + k * 256;
        *(float4*)&Lp[f * 4] = *(const float4*)&pj[f * 4];
    }
    __syncthreads();

    // ---- diffs; step 255 zero-padded (exact identity step) ----
    float4 dif[4];
#pragma unroll
    for (int k = 0; k < 4; ++k) {
        const int f = tid + k * 256;  // float4 index 0..1023
        if (f < 1020) {
            const float4 x0 = *(const float4*)&Lp[f * 4];
            const float4 x1 = *(const float4*)&Lp[f * 4 + 16];
            dif[k] = make_float4(x1.x - x0.x, x1.y - x0.y, x1.z - x0.z, x1.w - x0.w);
        } else {
            dif[k] = make_float4(0.f, 0.f, 0.f, 0.f);
        }
    }
    __syncthreads();
#pragma unroll
    for (int k = 0; k < 4; ++k) {
        const int f = tid + k * 256;
        *(float4*)&Lp[f * 4] = dif[k];
        const int t = f >> 2;            // time index 0..255
        const int i0 = 4 * (f & 3);      // component base
        Lc[(i0 + 0) * LCS + t] = dif[k].x;
        Lc[(i0 + 1) * LCS + t] = dif[k].y;
        Lc[(i0 + 2) * LCS + t] = dif[k].z;
        Lc[(i0 + 3) * LCS + t] = dif[k].w;
    }
    __syncthreads();

    // ---- phase 1: chunk-local scan (128 steps incl. zero step for h=1) ----
    v2f s4a[8], s4b[8];
#pragma unroll
    for (int d = 0; d < 8; ++d) { s4a[d] = (v2f){0.f, 0.f}; s4b[d] = (v2f){0.f, 0.f}; }
    float s3_0 = 0.f, s3_1 = 0.f, s2ab = 0.f, s1a = 0.f;

    int t = h * 128;
    for (int it = 0; it < 32; ++it, t += 4) {
        const float4 va = *(const float4*)(Lc + a * LCS + t);    // broadcast
        const float4 vb = *(const float4*)(Lc + b * LCS + t);    // conflict-free
        const float4 vc0 = *(const float4*)(Lc + c0 * LCS + t);
        const float4 vc1 = *(const float4*)(Lc + (c0 + 8) * LCS + t);
#pragma unroll
        for (int u = 0; u < 4; ++u) {
            const float* r = Lp + (t + u) * NC;   // uniform row, b128 broadcast
            const float4 q0 = *(const float4*)(r);
            const float4 q1 = *(const float4*)(r + 4);
            const float4 q2 = *(const float4*)(r + 8);
            const float4 q3 = *(const float4*)(r + 12);
            const float dxa = (u == 0) ? va.x : (u == 1) ? va.y : (u == 2) ? va.z : va.w;
            const float dxb = (u == 0) ? vb.x : (u == 1) ? vb.y : (u == 2) ? vb.z : vb.w;
            const float dxc0 = (u == 0) ? vc0.x : (u == 1) ? vc0.y : (u == 2) ? vc0.z : vc0.w;
            const float dxc1 = (u == 0) ? vc1.x : (u == 1) ? vc1.y : (u == 2) ? vc1.z : vc1.w;

            const float P = dxb * s1a;
            const float Q = dxb * dxa;
            const float pre4 = fmaf(1.f / 6.f, P, fmaf(1.f / 24.f, Q, 0.5f * s2ab));
            const float U = fmaf(0.5f, P, fmaf(1.f / 6.f, Q, s2ab));
            const float T0 = fmaf(dxc0, pre4, s3_0);
            const float T1 = fmaf(dxc1, pre4, s3_1);

            const v2f dv2[8] = {{q0.x, q0.y}, {q0.z, q0.w}, {q1.x, q1.y}, {q1.z, q1.w},
                                {q2.x, q2.y}, {q2.z, q2.w}, {q3.x, q3.y}, {q3.z, q3.w}};
            const v2f T0v = {T0, T0};
            const v2f T1v = {T1, T1};
#pragma unroll
            for (int d = 0; d < 8; ++d) {
                s4a[d] = __builtin_elementwise_fma(dv2[d], T0v, s4a[d]);  // v_pk_fma_f32
                s4b[d] = __builtin_elementwise_fma(dv2[d], T1v, s4b[d]);
            }
            s3_0 = fmaf(dxc0, U, s3_0);
            s3_1 = fmaf(dxc1, U, s3_1);
            s2ab = fmaf(dxb, fmaf(0.5f, dxa, s1a), s2ab);
            s1a += dxa;
        }
    }

    // ---- merge pure A4+B4 in LDS (both chunks live in this block) ----
    __syncthreads();
    float* ls = shA;  // Lp dead
    const int base = b * 256 + c0 * 16;
    if (h == 0) {
#pragma unroll
        for (int d = 0; d < 4; ++d) {
            *(float4*)&ls[base + d * 4] = make_float4(
                s4a[2 * d].x, s4a[2 * d].y, s4a[2 * d + 1].x, s4a[2 * d + 1].y);
            *(float4*)&ls[base + 128 + d * 4] = make_float4(
                s4b[2 * d].x, s4b[2 * d].y, s4b[2 * d + 1].x, s4b[2 * d + 1].y);
        }
    }
    __syncthreads();
    if (h == 1) {
#pragma unroll
        for (int d = 0; d < 4; ++d) {
            float4 v0 = *(const float4*)&ls[base + d * 4];
            v0.x += s4a[2 * d].x; v0.y += s4a[2 * d].y;
            v0.z += s4a[2 * d + 1].x; v0.w += s4a[2 * d + 1].y;
            *(float4*)&ls[base + d * 4] = v0;
            float4 v1 = *(const float4*)&ls[base + 128 + d * 4];
            v1.x += s4b[2 * d].x; v1.y += s4b[2 * d].y;
            v1.z += s4b[2 * d + 1].x; v1.w += s4b[2 * d + 1].y;
            *(float4*)&ls[base + 128 + d * 4] = v1;
        }
    }

    // ---- sig123 per chunk -> global ----
    float* sg = (h ? sigB : sigA) + (size_t)j * SIG123;
    sg[OFF_L3 + (a * 16 + b) * 16 + c0] = s3_0;
    sg[OFF_L3 + (a * 16 + b) * 16 + c0 + 8] = s3_1;
    if (c0 == 0) sg[OFF_L2 + a * 16 + b] = s2ab;
    if ((tid & 127) == 0) sg[a] = s1a;
    __syncthreads();

    if constexpr (!FUSED) {
        // fallback: write raw A4+B4 to out L4; k_log finishes.
        float* o4 = out + (size_t)j * OUTB + OFF_L4 + a * 4096;
#pragma unroll
        for (int k = 0; k < 4; ++k) {
            const int f = tid + k * 256;
            *(float4*)(o4 + f * 4) = *(const float4*)&ls[f * 4];
        }
        return;
    }

    __threadfence();
    cg::this_grid().sync();

    // ---- phase 2: Chen cross-terms + log correction (v4 k_log body) ----
    float* S3m = shB;            // 4096  (Lc dead)
    float* S2m = shB + 4096;     // 256
    float* B2s = shB + 4352;     // 256
    float* A3s = shB + 4608;     // 256
    float* S1m = shB + 4864;     // 16
    float* B1s = shB + 4880;     // 16
    float* A2s = shB + 4896;     // 16

    const int q = tid >> 4;
    const int r = tid & 15;
    const float* A = sigA + (size_t)j * SIG123;
    const float* Bp = sigB + (size_t)j * SIG123;

    const float b1r = Bp[r];             // B1[r]
    const float b2t = Bp[OFF_L2 + tid];  // B2[q,r]

    if (tid < 16) {
        const float bb = Bp[tid];
        B1s[tid] = bb;
        S1m[tid] = A[tid] + bb;               // S1 = A1 + B1
        A2s[tid] = A[OFF_L2 + a * 16 + tid];  // A2[a,:]
    }
    B2s[tid] = b2t;
    S2m[tid] = A[OFF_L2 + tid] + b2t + A[q] * b1r;  // S2 = A2 + B2 + A1(x)B1
    A3s[tid] = A[OFF_L3 + a * 256 + tid];           // A3[a,:,:]
#pragma unroll
    for (int k = 0; k < 16; ++k) {  // S3[p,q,r] = A3 + B3 + A1[p]B2[qr] + A2[pq]B1[r]
        const int m = k * 256 + tid;
        S3m[m] = A[OFF_L3 + m] + Bp[OFF_L3 + m] + A[k] * b2t + A[OFF_L2 + k * 16 + q] * b1r;
    }
    __syncthreads();

    const float s1a_m = S1m[a];
    const float A1a = A[a];
    float* outj = out + (size_t)j * OUTB;
    float* o4 = outj + OFF_L4 + a * 4096;
    const float Ac = -0.5f * s1a_m;

#pragma unroll
    for (int k = 0; k < 4; ++k) {
        const int f = tid + k * 256;
        const int m0 = f * 4;  // element offset: bb*256 + cc*16 + d0
        const int bb = m0 >> 8;
        const int cc = (m0 >> 4) & 15;
        const float s1b = S1m[bb], s1c = S1m[cc];
        const float s2ab_m = S2m[a * 16 + bb];
        const float s2bc = S2m[bb * 16 + cc];
        const float s3abc = S3m[a * 256 + (m0 >> 4)];  // merged S3[a,b,c]
        const float a3x = A3s[m0 >> 4];                // A3[a,b,c]
        const float a2x = A2s[bb];                     // A2[a,b]

        const float4 p4 = *(const float4*)&ls[m0];              // A4+B4 (LDS!)
        const float4 b3v = *(const float4*)(Bp + OFF_L3 + m0);  // B3[b,c,d..] (L2)
        const float4 b2v = *(const float4*)(&B2s[m0 & 255]);
        const float4 b1v = *(const float4*)(&B1s[m0 & 15]);
        const float4 v3 = *(const float4*)(&S3m[m0]);
        const float4 v2 = *(const float4*)(&S2m[m0 & 255]);
        const float4 v1 = *(const float4*)(&S1m[m0 & 15]);

        const float Bv = fmaf((1.f / 3.f) * s1a_m, s1b, -0.5f * s2ab_m);
        const float Cv = -0.5f * s3abc + (1.f / 3.f) * fmaf(s1a_m, s2bc, s2ab_m * s1c)
                         - 0.25f * s1a_m * s1b * s1c;
        float4 rv;
        // merged S4 = (A4+B4) + A1[a]B3[bcd] + A2[ab]B2[cd] + A3[abc]B1[d]
        rv.x = p4.x + fmaf(A1a, b3v.x, fmaf(a2x, b2v.x, a3x * b1v.x));
        rv.y = p4.y + fmaf(A1a, b3v.y, fmaf(a2x, b2v.y, a3x * b1v.y));
        rv.z = p4.z + fmaf(A1a, b3v.z, fmaf(a2x, b2v.z, a3x * b1v.z));
        rv.w = p4.w + fmaf(A1a, b3v.w, fmaf(a2x, b2v.w, a3x * b1v.w));
        // log correction
        rv.x = fmaf(Ac, v3.x, rv.x) + fmaf(Bv, v2.x, Cv * v1.x);
        rv.y = fmaf(Ac, v3.y, rv.y) + fmaf(Bv, v2.y, Cv * v1.y);
        rv.z = fmaf(Ac, v3.z, rv.z) + fmaf(Bv, v2.z, Cv * v1.z);
        rv.w = fmaf(Ac, v3.w, rv.w) + fmaf(Bv, v2.w, Cv * v1.w);
        *(float4*)(o4 + m0) = rv;
    }

    // level 3 (coalesced)
    {
        const float s1b = S1m[q], s1c = S1m[r];
        const float s2ab_m = S2m[a * 16 + q];
        const float s2bc = S2m[q * 16 + r];
        const float s3abc = S3m[a * 256 + tid];
        const float r3 = s3abc - 0.5f * fmaf(s1a_m, s2bc, s2ab_m * s1c)
                         + (1.f / 3.f) * s1a_m * s1b * s1c;
        outj[OFF_L3 + a * 256 + tid] = r3;
    }
    // level 2
    if (tid < 16) outj[OFF_L2 + a * 16 + tid] = fmaf(-0.5f * s1a_m, S1m[tid], S2m[a * 16 + tid]);
    // level 1
    if (tid == 0) outj[a] = s1a_m;
}

// Fallback second kernel (v4 k_log verbatim: RMW on out L4).
__global__ __launch_bounds__(256) void k_log(const float* __restrict__ sigA,
                                             const float* __restrict__ sigB,
                                             float* __restrict__ out) {
    const int bid = blockIdx.x;
    const int j = bid >> 4;
    const int a = bid & 15;
    const int tid = threadIdx.x;
    const int q = tid >> 4;
    const int r = tid & 15;

    const float* A = sigA + (size_t)j * SIG123;
    const float* Bp = sigB + (size_t)j * SIG123;

    __shared__ float S1m[16], B1s[16], A2s[16];
    __shared__ float S2m[256], B2s[256], A3s[256];
    __shared__ float S3m[4096];

    const float b1r = Bp[r];
    const float b2t = Bp[OFF_L2 + tid];

    if (tid < 16) {
        const float bb = Bp[tid];
        B1s[tid] = bb;
        S1m[tid] = A[tid] + bb;
        A2s[tid] = A[OFF_L2 + a * 16 + tid];
    }
    B2s[tid] = b2t;
    S2m[tid] = A[OFF_L2 + tid] + b2t + A[q] * b1r;
    A3s[tid] = A[OFF_L3 + a * 256 + tid];
#pragma unroll
    for (int k = 0; k < 16; ++k) {
        const int m = k * 256 + tid;
        S3m[m] = A[OFF_L3 + m] + Bp[OFF_L3 + m] + A[k] * b2t + A[OFF_L2 + k * 16 + q] * b1r;
    }
    __syncthreads();

    const float s1a = S1m[a];
    const float A1a = A[a];
    float* outj = out + (size_t)j * OUTB;
    float* o4 = outj + OFF_L4 + a * 4096;
    const float Ac = -0.5f * s1a;

#pragma unroll
    for (int k = 0; k < 4; ++k) {
        const int f = tid + k * 256;
        const int m0 = f * 4;
        const int bb = m0 >> 8;
        const int cc = (m0 >> 4) & 15;
        const float s1b = S1m[bb], s1c = S1m[cc];
        const float s2ab = S2m[a * 16 + bb];
        const float s2bc = S2m[bb * 16 + cc];
        const float s3abc = S3m[a * 256 + (m0 >> 4)];
        const float a3x = A3s[m0 >> 4];
        const float a2x = A2s[bb];

        const float4 a4 = *(const float4*)(o4 + m0);
        const float4 b3v = *(const float4*)(Bp + OFF_L3 + m0);
        const float4 b2v = *(const float4*)(&B2s[m0 & 255]);
        const float4 b1v = *(const float4*)(&B1s[m0 & 15]);
        const float4 v3 = *(const float4*)(&S3m[m0]);
        const float4 v2 = *(const float4*)(&S2m[m0 & 255]);
        const float4 v1 = *(const float4*)(&S1m[m0 & 15]);

        const float Bv = fmaf((1.f / 3.f) * s1a, s1b, -0.5f * s2ab);
        const float Cv = -0.5f * s3abc + (1.f / 3.f) * fmaf(s1a, s2bc, s2ab * s1c)
                         - 0.25f * s1a * s1b * s1c;
        float4 rv;
        rv.x = a4.x + fmaf(A1a, b3v.x, fmaf(a2x, b2v.x, a3x * b1v.x));
        rv.y = a4.y + fmaf(A1a, b3v.y, fmaf(a2x, b2v.y, a3x * b1v.y));
        rv.z = a4.z + fmaf(A1a, b3v.z, fmaf(a2x, b2v.z, a3x * b1v.z));
        rv.w = a4.w + fmaf(A1a, b3v.w, fmaf(a2x, b2v.w, a3x * b1v.w));
        rv.x = fmaf(Ac, v3.x, rv.x) + fmaf(Bv, v2.x, Cv * v1.x);
        rv.y = fmaf(Ac, v3.y, rv.y) + fmaf(Bv, v2.y, Cv * v1.y);
        rv.z = fmaf(Ac, v3.z, rv.z) + fmaf(Bv, v2.z, Cv * v1.z);
        rv.w = fmaf(Ac, v3.w, rv.w) + fmaf(Bv, v2.w, Cv * v1.w);
        *(float4*)(o4 + m0) = rv;
    }

    {
        const float s1b = S1m[q], s1c = S1m[r];
        const float s2ab = S2m[a * 16 + q];
        const float s2bc = S2m[q * 16 + r];
        const float s3abc = S3m[a * 256 + tid];
        const float r3 = s3abc - 0.5f * fmaf(s1a, s2bc, s2ab * s1c)
                         + (1.f / 3.f) * s1a * s1b * s1c;
        outj[OFF_L3 + a * 256 + tid] = r3;
    }
    if (tid < 16) outj[OFF_L2 + a * 16 + tid] = fmaf(-0.5f * s1a, S1m[tid], S2m[a * 16 + tid]);
    if (tid == 0) outj[a] = s1a;
}

extern "C" void kernel_launch(void* const* d_in, const int* in_sizes, int n_in,
                              void* d_out, int out_size, void* d_ws, size_t ws_size,
                              hipStream_t stream) {
    const float* path = (const float*)d_in[0];
    float* out = (float*)d_out;
    float* ws = (float*)d_ws;
    float* sigA = ws + SIGA_OFF;
    float* sigB = ws + SIGB_OFF;

    static int coop = -1;
    if (coop < 0) {
        int dev = 0;
        (void)hipGetDevice(&dev);
        int v = 0;
        if (hipDeviceGetAttribute(&v, hipDeviceAttributeCooperativeLaunch, dev) != hipSuccess)
            v = 0;
        coop = v;
    }

    if (coop) {
        void* args[] = {(void*)&path, (void*)&out, (void*)&sigA, (void*)&sigB};
        hipError_t e = hipLaunchCooperativeKernel((void*)k_fused<1>, dim3(NB * 16),
                                                  dim3(256), args, 0, stream);
        if (e == hipSuccess) return;
        coop = 0;  // fall through to split path
    }

    k_fused<0><<<NB * 16, 256, 0, stream>>>(path, out, sigA, sigB);
    k_log<<<NB * 16, 256, 0, stream>>>(sigA, sigB, out);
}